// Round 14
// baseline (324.345 us; speedup 1.0000x reference)
//
#include <hip/hip_runtime.h>
#include <hip/hip_bf16.h>
#include <math.h>
#include <stdio.h>

typedef __attribute__((ext_vector_type(8))) short short8;   // 8 bf16 (4 VGPRs)
typedef __attribute__((ext_vector_type(4))) float f32x4;
typedef __attribute__((ext_vector_type(4))) unsigned short us4;

__device__ __forceinline__ float us2f(unsigned short u) {
    return __uint_as_float(((unsigned)u) << 16);
}
__device__ __forceinline__ unsigned short f2us_rtn(float f) {
    return (unsigned short)__bfloat16_as_ushort(__float2bfloat16(f));  // RTN
}

// A-staging loaders: bf16 copy, or fp32 -> bf16 (RTN) convert
__device__ __forceinline__ void stage8(const unsigned short* Ap, unsigned short* dst) {
    *(short8*)dst = *(const short8*)Ap;
}
__device__ __forceinline__ void stage8(const float* Ap, unsigned short* dst) {
    const float4 a = *(const float4*)Ap;
    const float4 b = *(const float4*)(Ap + 4);
    const float f[8] = {a.x, a.y, a.z, a.w, b.x, b.y, b.z, b.w};
    short8 o;
#pragma unroll
    for (int e = 0; e < 8; e++) o[e] = (short)f2us_rtn(f[e]);
    *(short8*)dst = o;
}

// ---- prep: W^T bf16 x3 + zero-init (deg, as/ad x4) --------------------------
__global__ void prep_all(const float* __restrict__ Wa, const float* __restrict__ Wb,
                         const float* __restrict__ Wc,
                         unsigned short* __restrict__ TA, unsigned short* __restrict__ TB,
                         unsigned short* __restrict__ TC,
                         float* __restrict__ as1, float* __restrict__ ad1,
                         float* __restrict__ as2, float* __restrict__ ad2,
                         int* __restrict__ deg,
                         int K, int Nn, int N) {
    const int tot = K * Nn;
    int idx = blockIdx.x * blockDim.x + threadIdx.x;
    if (idx < 3 * tot) {
        const float* W;
        unsigned short* T;
        if (idx < tot) { W = Wa; T = TA; }
        else if (idx < 2 * tot) { W = Wb; T = TB; idx -= tot; }
        else { W = Wc; T = TC; idx -= 2 * tot; }
        const int n = idx / K, k = idx - n * K;
        T[idx] = f2us_rtn(W[(size_t)k * Nn + n]);
        return;
    }
    idx -= 3 * tot;
    if (idx < 5 * N) {
        if (idx < N) as1[idx] = 0.f;
        else if (idx < 2 * N) ad1[idx - N] = 0.f;
        else if (idx < 3 * N) as2[idx - 2 * N] = 0.f;
        else if (idx < 4 * N) ad2[idx - 3 * N] = 0.f;
        else deg[idx - 4 * N] = 0;
    }
}

#define LP 72
// ---------------- MFMA GEMM + fused dots (GAT layers 1/2) --------------------
// 64x128 tile/block, BK=64, 256 thr (4 waves 2x2). A fp32 or bf16; B bf16.
template <typename TA>
__global__ __launch_bounds__(256) void gemm_mfma(const TA* __restrict__ A,
                                                 const unsigned short* __restrict__ Bt,
                                                 const float* __restrict__ avs,
                                                 const float* __restrict__ avd,
                                                 float* __restrict__ as_,
                                                 float* __restrict__ ad_,
                                                 unsigned short* __restrict__ C,
                                                 int M, int Nn, int K) {
    __shared__ unsigned short sA[64 * LP];
    __shared__ unsigned short sB[128 * LP];
    const int tid = threadIdx.x;
    const int wave = tid >> 6, lane = tid & 63;
    const int m16 = lane & 15, quad = lane >> 4;
    const int row0 = blockIdx.x * 64, col0 = blockIdx.y * 128;
    const int wr = (wave >> 1) * 32, wc = (wave & 1) * 64;
    const int ar = tid >> 2, akc = (tid & 3) * 8;
    const int bkc = (tid & 7) * 8, bcb = tid >> 3;

    f32x4 acc[2][4] = {};
    for (int k0 = 0; k0 < K; k0 += 64) {
        {
            const int gr = (row0 + ar) < M ? (row0 + ar) : (M - 1);
            const TA* Ap = A + (size_t)gr * K + k0 + akc;
            stage8(Ap,      &sA[ar * LP + akc]);
            stage8(Ap + 32, &sA[ar * LP + akc + 32]);
        }
#pragma unroll
        for (int q = 0; q < 4; q++) {
            const int colq = bcb + 32 * q;
            *(short8*)&sB[colq * LP + bkc] =
                *(const short8*)(Bt + (size_t)(col0 + colq) * K + k0 + bkc);
        }
        __syncthreads();
#pragma unroll
        for (int ks = 0; ks < 2; ks++) {
            short8 ah[2];
#pragma unroll
            for (int mi = 0; mi < 2; mi++)
                ah[mi] = *(const short8*)&sA[(wr + mi * 16 + m16) * LP + ks * 32 + quad * 8];
#pragma unroll
            for (int ni = 0; ni < 4; ni++) {
                const short8 bv = *(const short8*)&sB[(wc + ni * 16 + m16) * LP + ks * 32 + quad * 8];
#pragma unroll
                for (int mi = 0; mi < 2; mi++)
                    acc[mi][ni] = __builtin_amdgcn_mfma_f32_16x16x32_bf16(ah[mi], bv, acc[mi][ni], 0, 0, 0);
            }
        }
        __syncthreads();
    }
    // epilogue: C/D layout col=lane&15, row=quad*4+r [m89-verified]
    float ps[2][4] = {}, pd[2][4] = {};
#pragma unroll
    for (int mi = 0; mi < 2; mi++) {
        const int orow_base = row0 + wr + mi * 16 + quad * 4;
#pragma unroll
        for (int ni = 0; ni < 4; ni++) {
            const int ocol = col0 + wc + ni * 16 + m16;
            const float asv = avs[ocol], adv = avd[ocol];
#pragma unroll
            for (int r = 0; r < 4; r++) {
                const int orow = orow_base + r;
                if (orow < M) {
                    const float v = acc[mi][ni][r];
                    C[(size_t)orow * Nn + ocol] = f2us_rtn(v);
                    ps[mi][r] = fmaf(v, asv, ps[mi][r]);
                    pd[mi][r] = fmaf(v, adv, pd[mi][r]);
                }
            }
        }
    }
#pragma unroll
    for (int mi = 0; mi < 2; mi++)
#pragma unroll
        for (int r = 0; r < 4; r++)
#pragma unroll
            for (int off = 1; off < 16; off <<= 1) {
                ps[mi][r] += __shfl_xor(ps[mi][r], off);
                pd[mi][r] += __shfl_xor(pd[mi][r], off);
            }
    if (m16 == 0) {
#pragma unroll
        for (int mi = 0; mi < 2; mi++) {
            const int orow_base = row0 + wr + mi * 16 + quad * 4;
#pragma unroll
            for (int r = 0; r < 4; r++) {
                const int orow = orow_base + r;
                if (orow < M) {
                    atomicAdd(&as_[orow], ps[mi][r]);
                    atomicAdd(&ad_[orow], pd[mi][r]);
                }
            }
        }
    }
}

// ---------------- MLP gemm + fused head: out = tanh(relu(x@Wm1+bm1)@Wm2+bm2) -
__global__ __launch_bounds__(256) void gemm_head(const unsigned short* __restrict__ A,
                                                 const unsigned short* __restrict__ Bt,
                                                 const float* __restrict__ bias1,
                                                 const float* __restrict__ W2,
                                                 const float* __restrict__ bias2,
                                                 float* __restrict__ out,
                                                 int M, int K, int Aout) {
    __shared__ unsigned short sA[64 * LP];
    __shared__ unsigned short sB[256 * LP];
    __shared__ float pLDS[2][64][8];
    const int tid = threadIdx.x;
    const int wave = tid >> 6, lane = tid & 63;
    const int m16 = lane & 15, quad = lane >> 4;
    const int row0 = blockIdx.x * 64;
    const int wr = (wave >> 1) * 32, wc = (wave & 1) * 128;
    const int ar = tid >> 2, akc = (tid & 3) * 8;
    const int bkc = (tid & 7) * 8, bcb = tid >> 3;

    f32x4 acc[2][8] = {};
    for (int k0 = 0; k0 < K; k0 += 64) {
        {
            const int gr = (row0 + ar) < M ? (row0 + ar) : (M - 1);
            const unsigned short* Ap = A + (size_t)gr * K + k0 + akc;
            *(short8*)&sA[ar * LP + akc]      = *(const short8*)Ap;
            *(short8*)&sA[ar * LP + akc + 32] = *(const short8*)(Ap + 32);
        }
#pragma unroll
        for (int q = 0; q < 8; q++) {
            const int colq = bcb + 32 * q;
            *(short8*)&sB[colq * LP + bkc] =
                *(const short8*)(Bt + (size_t)colq * K + k0 + bkc);
        }
        __syncthreads();
#pragma unroll
        for (int ks = 0; ks < 2; ks++) {
            short8 ah[2];
#pragma unroll
            for (int mi = 0; mi < 2; mi++)
                ah[mi] = *(const short8*)&sA[(wr + mi * 16 + m16) * LP + ks * 32 + quad * 8];
#pragma unroll
            for (int ni = 0; ni < 8; ni++) {
                const short8 bv = *(const short8*)&sB[(wc + ni * 16 + m16) * LP + ks * 32 + quad * 8];
#pragma unroll
                for (int mi = 0; mi < 2; mi++)
                    acc[mi][ni] = __builtin_amdgcn_mfma_f32_16x16x32_bf16(ah[mi], bv, acc[mi][ni], 0, 0, 0);
            }
        }
        __syncthreads();
    }
    float p[2][4][8] = {};
#pragma unroll
    for (int ni = 0; ni < 8; ni++) {
        const int ocol = wc + ni * 16 + m16;
        const float b1v = bias1[ocol];
        float w2[8];
#pragma unroll
        for (int a = 0; a < 8; a++) w2[a] = W2[ocol * 8 + a];
#pragma unroll
        for (int mi = 0; mi < 2; mi++)
#pragma unroll
            for (int r = 0; r < 4; r++) {
                const float v = fmaxf(acc[mi][ni][r] + b1v, 0.f);
#pragma unroll
                for (int a = 0; a < 8; a++) p[mi][r][a] = fmaf(v, w2[a], p[mi][r][a]);
            }
    }
#pragma unroll
    for (int off = 1; off < 16; off <<= 1)
#pragma unroll
        for (int mi = 0; mi < 2; mi++)
#pragma unroll
            for (int r = 0; r < 4; r++)
#pragma unroll
                for (int a = 0; a < 8; a++) p[mi][r][a] += __shfl_xor(p[mi][r][a], off);
    if (m16 == 0) {
        const int half = wc >> 7;
#pragma unroll
        for (int mi = 0; mi < 2; mi++) {
            const int lrow = wr + mi * 16 + quad * 4;
#pragma unroll
            for (int r = 0; r < 4; r++)
#pragma unroll
                for (int a = 0; a < 8; a++) pLDS[half][lrow + r][a] = p[mi][r][a];
        }
    }
    __syncthreads();
#pragma unroll
    for (int u = 0; u < 2; u++) {
        const int idx = tid * 2 + u;
        const int lrow = idx >> 3, a = idx & 7;
        const int orow = row0 + lrow;
        if (orow < M && a < Aout)
            out[(size_t)orow * Aout + a] =
                tanhf(pLDS[0][lrow][a] + pLDS[1][lrow][a] + bias2[a]);
    }
}
#undef LP

// ---------------- CSR build ----------------
__global__ void count_kernel(const int* __restrict__ dstA, int* __restrict__ deg, int E, int Etot) {
    const int e = blockIdx.x * blockDim.x + threadIdx.x;
    if (e >= Etot) return;
    const int d = (e < E) ? dstA[e] : (e - E);
    atomicAdd(&deg[d], 1);
}

__global__ __launch_bounds__(1024) void scan_kernel(const int* __restrict__ deg,
                                                    int* __restrict__ offs,
                                                    int* __restrict__ cursor, int N) {
    __shared__ int sums[1024];
    const int t = threadIdx.x;
    const int chunk = (N + 1023) / 1024;
    const int start = t * chunk;
    int s = 0;
    for (int i = 0; i < chunk; i++) {
        const int p = start + i;
        if (p < N) s += deg[p];
    }
    sums[t] = s;
    __syncthreads();
    for (int off = 1; off < 1024; off <<= 1) {
        const int add = (t >= off) ? sums[t - off] : 0;
        __syncthreads();
        sums[t] += add;
        __syncthreads();
    }
    int run = (t > 0) ? sums[t - 1] : 0;
    for (int i = 0; i < chunk; i++) {
        const int p = start + i;
        if (p < N) { offs[p] = run; cursor[p] = run; run += deg[p]; }
    }
    if (t == 0) offs[N] = sums[1023];
}

// writes src index into edata[slot].x
__global__ void scatter_kernel(const int* __restrict__ srcA, const int* __restrict__ dstA,
                               int* __restrict__ cursor, int2* __restrict__ edata, int E, int Etot) {
    const int e = blockIdx.x * blockDim.x + threadIdx.x;
    if (e >= Etot) return;
    int s, d;
    if (e < E) { s = srcA[e]; d = dstA[e]; } else { s = d = e - E; }
    const int slot = atomicAdd(&cursor[d], 1);
    edata[slot].x = s;
}

// ---- per-edge softmax weights: w_j = exp(leaky(as[s_j]+ad[n])), once/edge ---
// wave per node; writes edata[j].y = w (float bits), denom[n] = sum w
__global__ __launch_bounds__(256) void edge_alpha(const float* __restrict__ as_,
                                                  const float* __restrict__ ad_,
                                                  const int* __restrict__ offs,
                                                  int2* __restrict__ edata,
                                                  float* __restrict__ denom, int N) {
    const int n = blockIdx.x * 4 + (threadIdx.x >> 6);
    if (n >= N) return;
    const int lane = threadIdx.x & 63;
    const int b = offs[n], e2 = offs[n + 1];
    const float adn = ad_[n];
    float sum = 0.f;
    for (int j = b + lane; j < e2; j += 64) {
        const int s = edata[j].x;
        float v = as_[s] + adn;
        v = v > 0.f ? v : 0.2f * v;
        const float w = __expf(v);
        edata[j].y = __float_as_int(w);
        sum += w;
    }
#pragma unroll
    for (int off = 32; off; off >>= 1) sum += __shfl_down(sum, off);
    if (lane == 0) denom[n] = sum;
}

// ---- aggregation, XCD-sliced features, precomputed weights ------------------
// slice = blockIdx&3 -> per-XCD L2 working set = 20000 x 128B = 2.56 MB < 4 MB.
// Per edge: one broadcast 8B (s,w) load + one coalesced 128B h line + 1 fma.
__global__ __launch_bounds__(256) void agg_kernel(const unsigned short* __restrict__ hb,
                                                  const int* __restrict__ offs,
                                                  const int2* __restrict__ edata,
                                                  const float* __restrict__ denom,
                                                  const float* __restrict__ bias,
                                                  unsigned short* __restrict__ xout, int N) {
    const int bI = blockIdx.x;
    const int slice = bI & 3;
    const int n = (bI >> 2) * 4 + (threadIdx.x >> 6);
    if (n >= N) return;
    const int f = slice * 64 + (threadIdx.x & 63);
    const int b = offs[n], e2 = offs[n + 1];
    float acc = 0.f;
    int j = b;
    for (; j + 4 <= e2; j += 4) {
        int2 ew[4];
#pragma unroll
        for (int u = 0; u < 4; u++) ew[u] = edata[j + u];
        float hv[4];
#pragma unroll
        for (int u = 0; u < 4; u++) hv[u] = us2f(hb[(size_t)ew[u].x * 256 + f]);
#pragma unroll
        for (int u = 0; u < 4; u++) acc = fmaf(__int_as_float(ew[u].y), hv[u], acc);
    }
    for (; j < e2; j++) {
        const int2 ew = edata[j];
        acc = fmaf(__int_as_float(ew.y), us2f(hb[(size_t)ew.x * 256 + f]), acc);
    }
    const float r = fmaxf(acc / (denom[n] + 1e-16f) + bias[f], 0.f);
    xout[(size_t)n * 256 + f] = f2us_rtn(r);
}

extern "C" void kernel_launch(void* const* d_in, const int* in_sizes, int n_in,
                              void* d_out, int out_size, void* d_ws, size_t ws_size,
                              hipStream_t stream) {
    const float* obs = (const float*)d_in[0];
    const int* eidx  = (const int*)d_in[1];
    const float* W1  = (const float*)d_in[2];
    const float* a1s = (const float*)d_in[3];
    const float* a1d = (const float*)d_in[4];
    const float* b1  = (const float*)d_in[5];
    const float* W2  = (const float*)d_in[6];
    const float* a2s = (const float*)d_in[7];
    const float* a2d = (const float*)d_in[8];
    const float* b2v = (const float*)d_in[9];
    const float* Wm1 = (const float*)d_in[10];
    const float* bm1 = (const float*)d_in[11];
    const float* Wm2 = (const float*)d_in[12];
    const float* bm2 = (const float*)d_in[13];
    float* out = (float*)d_out;

    const int Hh = in_sizes[3];            // 256
    const int Dd = in_sizes[2] / Hh;       // 256
    const int N  = in_sizes[0] / Dd;       // 20000
    const int E  = in_sizes[1] / 2;        // 320000
    const int Etot = E + N;                // 340000 (with self-loops)
    const int Aout = in_sizes[12] / Hh;    // 8

    const int* srcA = eidx;
    const int* dstA = eidx + E;

    size_t off = 0;
    char* ws = (char*)d_ws;
    auto alloc = [&](size_t bytes) -> char* {
        char* p = ws + off;
        off = (off + bytes + 15) & ~(size_t)15;
        return p;
    };
    unsigned short* h  = (unsigned short*)alloc((size_t)N * Hh * 2);
    unsigned short* xb = (unsigned short*)alloc((size_t)N * Hh * 2);
    float* as1   = (float*)alloc((size_t)N * 4);
    float* ad1   = (float*)alloc((size_t)N * 4);
    float* as2   = (float*)alloc((size_t)N * 4);
    float* ad2   = (float*)alloc((size_t)N * 4);
    float* denom = (float*)alloc((size_t)N * 4);
    int* deg     = (int*)alloc((size_t)N * 4);
    int* offs    = (int*)alloc((size_t)(N + 1) * 4);
    int* cursor  = (int*)alloc((size_t)N * 4);
    int2* edata  = (int2*)alloc((size_t)Etot * 8);
    const size_t wsz = (size_t)Dd * Hh;    // 65536
    unsigned short* W1t = (unsigned short*)alloc(wsz * 2);
    unsigned short* W2t = (unsigned short*)alloc(wsz * 2);
    unsigned short* Wmt = (unsigned short*)alloc(wsz * 2);

    const int eb = 256;
    const int eg = (Etot + eb - 1) / eb;
    const dim3 ggrid((N + 63) / 64, Hh / 128);   // 313 x 2
    const int nrow = (N + 63) / 64;              // 313
    const int nb4 = (N + 3) / 4;
    const int agrid = nb4 * 4;                   // 4 slices per node-group

    // ---- prep ----
    const int ptot = 3 * (int)wsz + 5 * N;
    prep_all<<<(ptot + 255) / 256, 256, 0, stream>>>(
        W1, W2, Wm1, W1t, W2t, Wmt, as1, ad1, as2, ad2, deg, Dd, Hh, N);

    // ---- CSR build ----
    count_kernel<<<eg, eb, 0, stream>>>(dstA, deg, E, Etot);
    scan_kernel<<<1, 1024, 0, stream>>>(deg, offs, cursor, N);
    scatter_kernel<<<eg, eb, 0, stream>>>(srcA, dstA, cursor, edata, E, Etot);

    // ---- GAT layer 1 (fp32 A staged->bf16 in-kernel) ----
    gemm_mfma<float><<<ggrid, 256, 0, stream>>>(obs, W1t, a1s, a1d, as1, ad1, h, N, Hh, Dd);
    edge_alpha<<<nb4, 256, 0, stream>>>(as1, ad1, offs, edata, denom, N);
    agg_kernel<<<agrid, 256, 0, stream>>>(h, offs, edata, denom, b1, xb, N);

    // ---- GAT layer 2 ----
    gemm_mfma<unsigned short><<<ggrid, 256, 0, stream>>>(xb, W2t, a2s, a2d, as2, ad2, h, N, Hh, Hh);
    edge_alpha<<<nb4, 256, 0, stream>>>(as2, ad2, offs, edata, denom, N);
    agg_kernel<<<agrid, 256, 0, stream>>>(h, offs, edata, denom, b2v, xb, N);

    // ---- MLP + head (fused) ----
    gemm_head<<<nrow, 256, 0, stream>>>(xb, Wmt, bm1, Wm2, bm2, out, N, Hh, Aout);
}

// Round 15
// 308.013 us; speedup vs baseline: 1.0530x; 1.0530x over previous
//
#include <hip/hip_runtime.h>
#include <hip/hip_bf16.h>
#include <math.h>
#include <stdio.h>

typedef __attribute__((ext_vector_type(8))) short short8;   // 8 bf16 (4 VGPRs)
typedef __attribute__((ext_vector_type(4))) float f32x4;
typedef __attribute__((ext_vector_type(4))) unsigned short us4;

__device__ __forceinline__ float us2f(unsigned short u) {
    return __uint_as_float(((unsigned)u) << 16);
}
__device__ __forceinline__ unsigned short f2us_rtn(float f) {
    return (unsigned short)__bfloat16_as_ushort(__float2bfloat16(f));  // RTN
}

// A-staging loaders: bf16 copy, or fp32 -> bf16 (RTN) convert
__device__ __forceinline__ void stage8(const unsigned short* Ap, unsigned short* dst) {
    *(short8*)dst = *(const short8*)Ap;
}
__device__ __forceinline__ void stage8(const float* Ap, unsigned short* dst) {
    const float4 a = *(const float4*)Ap;
    const float4 b = *(const float4*)(Ap + 4);
    const float f[8] = {a.x, a.y, a.z, a.w, b.x, b.y, b.z, b.w};
    short8 o;
#pragma unroll
    for (int e = 0; e < 8; e++) o[e] = (short)f2us_rtn(f[e]);
    *(short8*)dst = o;
}

// ---- prep: W^T bf16 x3 + zero-init (deg, as/ad x4) --------------------------
__global__ void prep_all(const float* __restrict__ Wa, const float* __restrict__ Wb,
                         const float* __restrict__ Wc,
                         unsigned short* __restrict__ TA, unsigned short* __restrict__ TB,
                         unsigned short* __restrict__ TC,
                         float* __restrict__ as1, float* __restrict__ ad1,
                         float* __restrict__ as2, float* __restrict__ ad2,
                         int* __restrict__ deg,
                         int K, int Nn, int N) {
    const int tot = K * Nn;
    int idx = blockIdx.x * blockDim.x + threadIdx.x;
    if (idx < 3 * tot) {
        const float* W;
        unsigned short* T;
        if (idx < tot) { W = Wa; T = TA; }
        else if (idx < 2 * tot) { W = Wb; T = TB; idx -= tot; }
        else { W = Wc; T = TC; idx -= 2 * tot; }
        const int n = idx / K, k = idx - n * K;
        T[idx] = f2us_rtn(W[(size_t)k * Nn + n]);
        return;
    }
    idx -= 3 * tot;
    if (idx < 5 * N) {
        if (idx < N) as1[idx] = 0.f;
        else if (idx < 2 * N) ad1[idx - N] = 0.f;
        else if (idx < 3 * N) as2[idx - 2 * N] = 0.f;
        else if (idx < 4 * N) ad2[idx - 3 * N] = 0.f;
        else deg[idx - 4 * N] = 0;
    }
}

#define LP 72
// ---------------- MFMA GEMM + fused dots (GAT layers 1/2) --------------------
// 64x128 tile/block, BK=64, 256 thr (4 waves 2x2). A fp32 or bf16; B bf16.
template <typename TA>
__global__ __launch_bounds__(256) void gemm_mfma(const TA* __restrict__ A,
                                                 const unsigned short* __restrict__ Bt,
                                                 const float* __restrict__ avs,
                                                 const float* __restrict__ avd,
                                                 float* __restrict__ as_,
                                                 float* __restrict__ ad_,
                                                 unsigned short* __restrict__ C,
                                                 int M, int Nn, int K) {
    __shared__ unsigned short sA[64 * LP];
    __shared__ unsigned short sB[128 * LP];
    const int tid = threadIdx.x;
    const int wave = tid >> 6, lane = tid & 63;
    const int m16 = lane & 15, quad = lane >> 4;
    const int row0 = blockIdx.x * 64, col0 = blockIdx.y * 128;
    const int wr = (wave >> 1) * 32, wc = (wave & 1) * 64;
    const int ar = tid >> 2, akc = (tid & 3) * 8;
    const int bkc = (tid & 7) * 8, bcb = tid >> 3;

    f32x4 acc[2][4] = {};
    for (int k0 = 0; k0 < K; k0 += 64) {
        {
            const int gr = (row0 + ar) < M ? (row0 + ar) : (M - 1);
            const TA* Ap = A + (size_t)gr * K + k0 + akc;
            stage8(Ap,      &sA[ar * LP + akc]);
            stage8(Ap + 32, &sA[ar * LP + akc + 32]);
        }
#pragma unroll
        for (int q = 0; q < 4; q++) {
            const int colq = bcb + 32 * q;
            *(short8*)&sB[colq * LP + bkc] =
                *(const short8*)(Bt + (size_t)(col0 + colq) * K + k0 + bkc);
        }
        __syncthreads();
#pragma unroll
        for (int ks = 0; ks < 2; ks++) {
            short8 ah[2];
#pragma unroll
            for (int mi = 0; mi < 2; mi++)
                ah[mi] = *(const short8*)&sA[(wr + mi * 16 + m16) * LP + ks * 32 + quad * 8];
#pragma unroll
            for (int ni = 0; ni < 4; ni++) {
                const short8 bv = *(const short8*)&sB[(wc + ni * 16 + m16) * LP + ks * 32 + quad * 8];
#pragma unroll
                for (int mi = 0; mi < 2; mi++)
                    acc[mi][ni] = __builtin_amdgcn_mfma_f32_16x16x32_bf16(ah[mi], bv, acc[mi][ni], 0, 0, 0);
            }
        }
        __syncthreads();
    }
    // epilogue: C/D layout col=lane&15, row=quad*4+r [m89-verified]
    float ps[2][4] = {}, pd[2][4] = {};
#pragma unroll
    for (int mi = 0; mi < 2; mi++) {
        const int orow_base = row0 + wr + mi * 16 + quad * 4;
#pragma unroll
        for (int ni = 0; ni < 4; ni++) {
            const int ocol = col0 + wc + ni * 16 + m16;
            const float asv = avs[ocol], adv = avd[ocol];
#pragma unroll
            for (int r = 0; r < 4; r++) {
                const int orow = orow_base + r;
                if (orow < M) {
                    const float v = acc[mi][ni][r];
                    C[(size_t)orow * Nn + ocol] = f2us_rtn(v);
                    ps[mi][r] = fmaf(v, asv, ps[mi][r]);
                    pd[mi][r] = fmaf(v, adv, pd[mi][r]);
                }
            }
        }
    }
#pragma unroll
    for (int mi = 0; mi < 2; mi++)
#pragma unroll
        for (int r = 0; r < 4; r++)
#pragma unroll
            for (int off = 1; off < 16; off <<= 1) {
                ps[mi][r] += __shfl_xor(ps[mi][r], off);
                pd[mi][r] += __shfl_xor(pd[mi][r], off);
            }
    if (m16 == 0) {
#pragma unroll
        for (int mi = 0; mi < 2; mi++) {
            const int orow_base = row0 + wr + mi * 16 + quad * 4;
#pragma unroll
            for (int r = 0; r < 4; r++) {
                const int orow = orow_base + r;
                if (orow < M) {
                    atomicAdd(&as_[orow], ps[mi][r]);
                    atomicAdd(&ad_[orow], pd[mi][r]);
                }
            }
        }
    }
}

// ---------------- MLP gemm + fused head: out = tanh(relu(x@Wm1+bm1)@Wm2+bm2) -
__global__ __launch_bounds__(256) void gemm_head(const unsigned short* __restrict__ A,
                                                 const unsigned short* __restrict__ Bt,
                                                 const float* __restrict__ bias1,
                                                 const float* __restrict__ W2,
                                                 const float* __restrict__ bias2,
                                                 float* __restrict__ out,
                                                 int M, int K, int Aout) {
    __shared__ unsigned short sA[64 * LP];
    __shared__ unsigned short sB[256 * LP];
    __shared__ float pLDS[2][64][8];
    const int tid = threadIdx.x;
    const int wave = tid >> 6, lane = tid & 63;
    const int m16 = lane & 15, quad = lane >> 4;
    const int row0 = blockIdx.x * 64;
    const int wr = (wave >> 1) * 32, wc = (wave & 1) * 128;
    const int ar = tid >> 2, akc = (tid & 3) * 8;
    const int bkc = (tid & 7) * 8, bcb = tid >> 3;

    f32x4 acc[2][8] = {};
    for (int k0 = 0; k0 < K; k0 += 64) {
        {
            const int gr = (row0 + ar) < M ? (row0 + ar) : (M - 1);
            const unsigned short* Ap = A + (size_t)gr * K + k0 + akc;
            *(short8*)&sA[ar * LP + akc]      = *(const short8*)Ap;
            *(short8*)&sA[ar * LP + akc + 32] = *(const short8*)(Ap + 32);
        }
#pragma unroll
        for (int q = 0; q < 8; q++) {
            const int colq = bcb + 32 * q;
            *(short8*)&sB[colq * LP + bkc] =
                *(const short8*)(Bt + (size_t)colq * K + k0 + bkc);
        }
        __syncthreads();
#pragma unroll
        for (int ks = 0; ks < 2; ks++) {
            short8 ah[2];
#pragma unroll
            for (int mi = 0; mi < 2; mi++)
                ah[mi] = *(const short8*)&sA[(wr + mi * 16 + m16) * LP + ks * 32 + quad * 8];
#pragma unroll
            for (int ni = 0; ni < 8; ni++) {
                const short8 bv = *(const short8*)&sB[(wc + ni * 16 + m16) * LP + ks * 32 + quad * 8];
#pragma unroll
                for (int mi = 0; mi < 2; mi++)
                    acc[mi][ni] = __builtin_amdgcn_mfma_f32_16x16x32_bf16(ah[mi], bv, acc[mi][ni], 0, 0, 0);
            }
        }
        __syncthreads();
    }
    float p[2][4][8] = {};
#pragma unroll
    for (int ni = 0; ni < 8; ni++) {
        const int ocol = wc + ni * 16 + m16;
        const float b1v = bias1[ocol];
        float w2[8];
#pragma unroll
        for (int a = 0; a < 8; a++) w2[a] = W2[ocol * 8 + a];
#pragma unroll
        for (int mi = 0; mi < 2; mi++)
#pragma unroll
            for (int r = 0; r < 4; r++) {
                const float v = fmaxf(acc[mi][ni][r] + b1v, 0.f);
#pragma unroll
                for (int a = 0; a < 8; a++) p[mi][r][a] = fmaf(v, w2[a], p[mi][r][a]);
            }
    }
#pragma unroll
    for (int off = 1; off < 16; off <<= 1)
#pragma unroll
        for (int mi = 0; mi < 2; mi++)
#pragma unroll
            for (int r = 0; r < 4; r++)
#pragma unroll
                for (int a = 0; a < 8; a++) p[mi][r][a] += __shfl_xor(p[mi][r][a], off);
    if (m16 == 0) {
        const int half = wc >> 7;
#pragma unroll
        for (int mi = 0; mi < 2; mi++) {
            const int lrow = wr + mi * 16 + quad * 4;
#pragma unroll
            for (int r = 0; r < 4; r++)
#pragma unroll
                for (int a = 0; a < 8; a++) pLDS[half][lrow + r][a] = p[mi][r][a];
        }
    }
    __syncthreads();
#pragma unroll
    for (int u = 0; u < 2; u++) {
        const int idx = tid * 2 + u;
        const int lrow = idx >> 3, a = idx & 7;
        const int orow = row0 + lrow;
        if (orow < M && a < Aout)
            out[(size_t)orow * Aout + a] =
                tanhf(pLDS[0][lrow][a] + pLDS[1][lrow][a] + bias2[a]);
    }
}
#undef LP

// ---------------- CSR build ----------------
__global__ void count_kernel(const int* __restrict__ dstA, int* __restrict__ deg, int E, int Etot) {
    const int e = blockIdx.x * blockDim.x + threadIdx.x;
    if (e >= Etot) return;
    const int d = (e < E) ? dstA[e] : (e - E);
    atomicAdd(&deg[d], 1);
}

__global__ __launch_bounds__(1024) void scan_kernel(const int* __restrict__ deg,
                                                    int* __restrict__ offs,
                                                    int* __restrict__ cursor, int N) {
    __shared__ int sums[1024];
    const int t = threadIdx.x;
    const int chunk = (N + 1023) / 1024;
    const int start = t * chunk;
    int s = 0;
    for (int i = 0; i < chunk; i++) {
        const int p = start + i;
        if (p < N) s += deg[p];
    }
    sums[t] = s;
    __syncthreads();
    for (int off = 1; off < 1024; off <<= 1) {
        const int add = (t >= off) ? sums[t - off] : 0;
        __syncthreads();
        sums[t] += add;
        __syncthreads();
    }
    int run = (t > 0) ? sums[t - 1] : 0;
    for (int i = 0; i < chunk; i++) {
        const int p = start + i;
        if (p < N) { offs[p] = run; cursor[p] = run; run += deg[p]; }
    }
    if (t == 0) offs[N] = sums[1023];
}

// writes src index into edata[slot].x
__global__ void scatter_kernel(const int* __restrict__ srcA, const int* __restrict__ dstA,
                               int* __restrict__ cursor, int2* __restrict__ edata, int E, int Etot) {
    const int e = blockIdx.x * blockDim.x + threadIdx.x;
    if (e >= Etot) return;
    int s, d;
    if (e < E) { s = srcA[e]; d = dstA[e]; } else { s = d = e - E; }
    const int slot = atomicAdd(&cursor[d], 1);
    edata[slot].x = s;
}

// ---- per-edge softmax weights: w_j = exp(leaky(as[s_j]+ad[n])), once/edge ---
__global__ __launch_bounds__(256) void edge_alpha(const float* __restrict__ as_,
                                                  const float* __restrict__ ad_,
                                                  const int* __restrict__ offs,
                                                  int2* __restrict__ edata,
                                                  float* __restrict__ denom, int N) {
    const int n = blockIdx.x * 4 + (threadIdx.x >> 6);
    if (n >= N) return;
    const int lane = threadIdx.x & 63;
    const int b = offs[n], e2 = offs[n + 1];
    const float adn = ad_[n];
    float sum = 0.f;
    for (int j = b + lane; j < e2; j += 64) {
        const int s = edata[j].x;
        float v = as_[s] + adn;
        v = v > 0.f ? v : 0.2f * v;
        const float w = __expf(v);
        edata[j].y = __float_as_int(w);
        sum += w;
    }
#pragma unroll
    for (int off = 32; off; off >>= 1) sum += __shfl_down(sum, off);
    if (lane == 0) denom[n] = sum;
}

// ---- aggregation: XCD-sliced + 16-edge MLP unroll + scalar-path edata -------
// slice = blockIdx&3 -> per-XCD h working set = 20000 x 128B = 2.56 MB < 4 MB L2.
// n forced wave-uniform (readfirstlane) so offs/edata/denom use scalar loads;
// vector pipe carries only the 16-deep h-line gather (MLP restored vs R14).
__global__ __launch_bounds__(256) void agg_kernel(const unsigned short* __restrict__ hb,
                                                  const int* __restrict__ offs,
                                                  const int2* __restrict__ edata,
                                                  const float* __restrict__ denom,
                                                  const float* __restrict__ bias,
                                                  unsigned short* __restrict__ xout, int N) {
    const int bI = blockIdx.x;
    const int slice = bI & 3;
    const int n = __builtin_amdgcn_readfirstlane((bI >> 2) * 4 + (threadIdx.x >> 6));
    if (n >= N) return;
    const int f = slice * 64 + (threadIdx.x & 63);
    const int b = offs[n], e2 = offs[n + 1];
    float acc = 0.f;
    for (int j = b; j < e2; j += 16) {
        float w[16];
        int src[16];
#pragma unroll
        for (int u = 0; u < 16; u++) {
            const int jj = (j + u < e2) ? (j + u) : (e2 - 1);   // clamp: self-loop guarantees valid
            const int2 ew = edata[jj];
            src[u] = ew.x;
            w[u] = (j + u < e2) ? __int_as_float(ew.y) : 0.f;
        }
        float hv[16];
#pragma unroll
        for (int u = 0; u < 16; u++) hv[u] = us2f(hb[(unsigned)((src[u] << 8) + f)]);
#pragma unroll
        for (int u = 0; u < 16; u++) acc = fmaf(w[u], hv[u], acc);
    }
    const float r = fmaxf(acc / (denom[n] + 1e-16f) + bias[f], 0.f);
    xout[(unsigned)((n << 8) + f)] = f2us_rtn(r);
}

extern "C" void kernel_launch(void* const* d_in, const int* in_sizes, int n_in,
                              void* d_out, int out_size, void* d_ws, size_t ws_size,
                              hipStream_t stream) {
    const float* obs = (const float*)d_in[0];
    const int* eidx  = (const int*)d_in[1];
    const float* W1  = (const float*)d_in[2];
    const float* a1s = (const float*)d_in[3];
    const float* a1d = (const float*)d_in[4];
    const float* b1  = (const float*)d_in[5];
    const float* W2  = (const float*)d_in[6];
    const float* a2s = (const float*)d_in[7];
    const float* a2d = (const float*)d_in[8];
    const float* b2v = (const float*)d_in[9];
    const float* Wm1 = (const float*)d_in[10];
    const float* bm1 = (const float*)d_in[11];
    const float* Wm2 = (const float*)d_in[12];
    const float* bm2 = (const float*)d_in[13];
    float* out = (float*)d_out;

    const int Hh = in_sizes[3];            // 256
    const int Dd = in_sizes[2] / Hh;       // 256
    const int N  = in_sizes[0] / Dd;       // 20000
    const int E  = in_sizes[1] / 2;        // 320000
    const int Etot = E + N;                // 340000 (with self-loops)
    const int Aout = in_sizes[12] / Hh;    // 8

    const int* srcA = eidx;
    const int* dstA = eidx + E;

    size_t off = 0;
    char* ws = (char*)d_ws;
    auto alloc = [&](size_t bytes) -> char* {
        char* p = ws + off;
        off = (off + bytes + 15) & ~(size_t)15;
        return p;
    };
    unsigned short* h  = (unsigned short*)alloc((size_t)N * Hh * 2);
    unsigned short* xb = (unsigned short*)alloc((size_t)N * Hh * 2);
    float* as1   = (float*)alloc((size_t)N * 4);
    float* ad1   = (float*)alloc((size_t)N * 4);
    float* as2   = (float*)alloc((size_t)N * 4);
    float* ad2   = (float*)alloc((size_t)N * 4);
    float* denom = (float*)alloc((size_t)N * 4);
    int* deg     = (int*)alloc((size_t)N * 4);
    int* offs    = (int*)alloc((size_t)(N + 1) * 4);
    int* cursor  = (int*)alloc((size_t)N * 4);
    int2* edata  = (int2*)alloc((size_t)Etot * 8);
    const size_t wsz = (size_t)Dd * Hh;    // 65536
    unsigned short* W1t = (unsigned short*)alloc(wsz * 2);
    unsigned short* W2t = (unsigned short*)alloc(wsz * 2);
    unsigned short* Wmt = (unsigned short*)alloc(wsz * 2);

    const int eb = 256;
    const int eg = (Etot + eb - 1) / eb;
    const dim3 ggrid((N + 63) / 64, Hh / 128);   // 313 x 2
    const int nrow = (N + 63) / 64;              // 313
    const int nb4 = (N + 3) / 4;
    const int agrid = nb4 * 4;                   // 4 slices per node-group

    // ---- prep ----
    const int ptot = 3 * (int)wsz + 5 * N;
    prep_all<<<(ptot + 255) / 256, 256, 0, stream>>>(
        W1, W2, Wm1, W1t, W2t, Wmt, as1, ad1, as2, ad2, deg, Dd, Hh, N);

    // ---- CSR build ----
    count_kernel<<<eg, eb, 0, stream>>>(dstA, deg, E, Etot);
    scan_kernel<<<1, 1024, 0, stream>>>(deg, offs, cursor, N);
    scatter_kernel<<<eg, eb, 0, stream>>>(srcA, dstA, cursor, edata, E, Etot);

    // ---- GAT layer 1 (fp32 A staged->bf16 in-kernel) ----
    gemm_mfma<float><<<ggrid, 256, 0, stream>>>(obs, W1t, a1s, a1d, as1, ad1, h, N, Hh, Dd);
    edge_alpha<<<nb4, 256, 0, stream>>>(as1, ad1, offs, edata, denom, N);
    agg_kernel<<<agrid, 256, 0, stream>>>(h, offs, edata, denom, b1, xb, N);

    // ---- GAT layer 2 ----
    gemm_mfma<unsigned short><<<ggrid, 256, 0, stream>>>(xb, W2t, a2s, a2d, as2, ad2, h, N, Hh, Hh);
    edge_alpha<<<nb4, 256, 0, stream>>>(as2, ad2, offs, edata, denom, N);
    agg_kernel<<<agrid, 256, 0, stream>>>(h, offs, edata, denom, b2v, xb, N);

    // ---- MLP + head (fused) ----
    gemm_head<<<nrow, 256, 0, stream>>>(xb, Wmt, bm1, Wm2, bm2, out, N, Hh, Aout);
}

// Round 16
// 270.296 us; speedup vs baseline: 1.2000x; 1.1395x over previous
//
#include <hip/hip_runtime.h>
#include <hip/hip_bf16.h>
#include <math.h>
#include <stdio.h>

typedef __attribute__((ext_vector_type(8))) short short8;   // 8 bf16 (4 VGPRs)
typedef __attribute__((ext_vector_type(4))) float f32x4;
typedef __attribute__((ext_vector_type(4))) unsigned short us4;

__device__ __forceinline__ float us2f(unsigned short u) {
    return __uint_as_float(((unsigned)u) << 16);
}
__device__ __forceinline__ unsigned short f2us_rtn(float f) {
    return (unsigned short)__bfloat16_as_ushort(__float2bfloat16(f));  // RTN
}

// A-staging loaders: bf16 copy, or fp32 -> bf16 (RTN) convert
__device__ __forceinline__ void stage8(const unsigned short* Ap, unsigned short* dst) {
    *(short8*)dst = *(const short8*)Ap;
}
__device__ __forceinline__ void stage8(const float* Ap, unsigned short* dst) {
    const float4 a = *(const float4*)Ap;
    const float4 b = *(const float4*)(Ap + 4);
    const float f[8] = {a.x, a.y, a.z, a.w, b.x, b.y, b.z, b.w};
    short8 o;
#pragma unroll
    for (int e = 0; e < 8; e++) o[e] = (short)f2us_rtn(f[e]);
    *(short8*)dst = o;
}

// ---- prep: W^T bf16 x3 + zero-init (deg, as/ad x4) --------------------------
__global__ void prep_all(const float* __restrict__ Wa, const float* __restrict__ Wb,
                         const float* __restrict__ Wc,
                         unsigned short* __restrict__ TA, unsigned short* __restrict__ TB,
                         unsigned short* __restrict__ TC,
                         float* __restrict__ as1, float* __restrict__ ad1,
                         float* __restrict__ as2, float* __restrict__ ad2,
                         int* __restrict__ deg,
                         int K, int Nn, int N) {
    const int tot = K * Nn;
    int idx = blockIdx.x * blockDim.x + threadIdx.x;
    if (idx < 3 * tot) {
        const float* W;
        unsigned short* T;
        if (idx < tot) { W = Wa; T = TA; }
        else if (idx < 2 * tot) { W = Wb; T = TB; idx -= tot; }
        else { W = Wc; T = TC; idx -= 2 * tot; }
        const int n = idx / K, k = idx - n * K;
        T[idx] = f2us_rtn(W[(size_t)k * Nn + n]);
        return;
    }
    idx -= 3 * tot;
    if (idx < 5 * N) {
        if (idx < N) as1[idx] = 0.f;
        else if (idx < 2 * N) ad1[idx - N] = 0.f;
        else if (idx < 3 * N) as2[idx - 2 * N] = 0.f;
        else if (idx < 4 * N) ad2[idx - 3 * N] = 0.f;
        else deg[idx - 4 * N] = 0;
    }
}

#define LP 72
// ---------------- MFMA GEMM + fused dots (GAT layers 1/2) --------------------
// 64x128 tile/block, BK=64, 256 thr (4 waves 2x2). A fp32 or bf16; B bf16.
template <typename TA>
__global__ __launch_bounds__(256) void gemm_mfma(const TA* __restrict__ A,
                                                 const unsigned short* __restrict__ Bt,
                                                 const float* __restrict__ avs,
                                                 const float* __restrict__ avd,
                                                 float* __restrict__ as_,
                                                 float* __restrict__ ad_,
                                                 unsigned short* __restrict__ C,
                                                 int M, int Nn, int K) {
    __shared__ unsigned short sA[64 * LP];
    __shared__ unsigned short sB[128 * LP];
    const int tid = threadIdx.x;
    const int wave = tid >> 6, lane = tid & 63;
    const int m16 = lane & 15, quad = lane >> 4;
    const int row0 = blockIdx.x * 64, col0 = blockIdx.y * 128;
    const int wr = (wave >> 1) * 32, wc = (wave & 1) * 64;
    const int ar = tid >> 2, akc = (tid & 3) * 8;
    const int bkc = (tid & 7) * 8, bcb = tid >> 3;

    f32x4 acc[2][4] = {};
    for (int k0 = 0; k0 < K; k0 += 64) {
        {
            const int gr = (row0 + ar) < M ? (row0 + ar) : (M - 1);
            const TA* Ap = A + (size_t)gr * K + k0 + akc;
            stage8(Ap,      &sA[ar * LP + akc]);
            stage8(Ap + 32, &sA[ar * LP + akc + 32]);
        }
#pragma unroll
        for (int q = 0; q < 4; q++) {
            const int colq = bcb + 32 * q;
            *(short8*)&sB[colq * LP + bkc] =
                *(const short8*)(Bt + (size_t)(col0 + colq) * K + k0 + bkc);
        }
        __syncthreads();
#pragma unroll
        for (int ks = 0; ks < 2; ks++) {
            short8 ah[2];
#pragma unroll
            for (int mi = 0; mi < 2; mi++)
                ah[mi] = *(const short8*)&sA[(wr + mi * 16 + m16) * LP + ks * 32 + quad * 8];
#pragma unroll
            for (int ni = 0; ni < 4; ni++) {
                const short8 bv = *(const short8*)&sB[(wc + ni * 16 + m16) * LP + ks * 32 + quad * 8];
#pragma unroll
                for (int mi = 0; mi < 2; mi++)
                    acc[mi][ni] = __builtin_amdgcn_mfma_f32_16x16x32_bf16(ah[mi], bv, acc[mi][ni], 0, 0, 0);
            }
        }
        __syncthreads();
    }
    // epilogue: C/D layout col=lane&15, row=quad*4+r [m89-verified]
    float ps[2][4] = {}, pd[2][4] = {};
#pragma unroll
    for (int mi = 0; mi < 2; mi++) {
        const int orow_base = row0 + wr + mi * 16 + quad * 4;
#pragma unroll
        for (int ni = 0; ni < 4; ni++) {
            const int ocol = col0 + wc + ni * 16 + m16;
            const float asv = avs[ocol], adv = avd[ocol];
#pragma unroll
            for (int r = 0; r < 4; r++) {
                const int orow = orow_base + r;
                if (orow < M) {
                    const float v = acc[mi][ni][r];
                    C[(size_t)orow * Nn + ocol] = f2us_rtn(v);
                    ps[mi][r] = fmaf(v, asv, ps[mi][r]);
                    pd[mi][r] = fmaf(v, adv, pd[mi][r]);
                }
            }
        }
    }
#pragma unroll
    for (int mi = 0; mi < 2; mi++)
#pragma unroll
        for (int r = 0; r < 4; r++)
#pragma unroll
            for (int off = 1; off < 16; off <<= 1) {
                ps[mi][r] += __shfl_xor(ps[mi][r], off);
                pd[mi][r] += __shfl_xor(pd[mi][r], off);
            }
    if (m16 == 0) {
#pragma unroll
        for (int mi = 0; mi < 2; mi++) {
            const int orow_base = row0 + wr + mi * 16 + quad * 4;
#pragma unroll
            for (int r = 0; r < 4; r++) {
                const int orow = orow_base + r;
                if (orow < M) {
                    atomicAdd(&as_[orow], ps[mi][r]);
                    atomicAdd(&ad_[orow], pd[mi][r]);
                }
            }
        }
    }
}

// ---------------- MLP gemm + fused head: out = tanh(relu(x@Wm1+bm1)@Wm2+bm2) -
__global__ __launch_bounds__(256) void gemm_head(const unsigned short* __restrict__ A,
                                                 const unsigned short* __restrict__ Bt,
                                                 const float* __restrict__ bias1,
                                                 const float* __restrict__ W2,
                                                 const float* __restrict__ bias2,
                                                 float* __restrict__ out,
                                                 int M, int K, int Aout) {
    __shared__ unsigned short sA[64 * LP];
    __shared__ unsigned short sB[256 * LP];
    __shared__ float pLDS[2][64][8];
    const int tid = threadIdx.x;
    const int wave = tid >> 6, lane = tid & 63;
    const int m16 = lane & 15, quad = lane >> 4;
    const int row0 = blockIdx.x * 64;
    const int wr = (wave >> 1) * 32, wc = (wave & 1) * 128;
    const int ar = tid >> 2, akc = (tid & 3) * 8;
    const int bkc = (tid & 7) * 8, bcb = tid >> 3;

    f32x4 acc[2][8] = {};
    for (int k0 = 0; k0 < K; k0 += 64) {
        {
            const int gr = (row0 + ar) < M ? (row0 + ar) : (M - 1);
            const unsigned short* Ap = A + (size_t)gr * K + k0 + akc;
            *(short8*)&sA[ar * LP + akc]      = *(const short8*)Ap;
            *(short8*)&sA[ar * LP + akc + 32] = *(const short8*)(Ap + 32);
        }
#pragma unroll
        for (int q = 0; q < 8; q++) {
            const int colq = bcb + 32 * q;
            *(short8*)&sB[colq * LP + bkc] =
                *(const short8*)(Bt + (size_t)colq * K + k0 + bkc);
        }
        __syncthreads();
#pragma unroll
        for (int ks = 0; ks < 2; ks++) {
            short8 ah[2];
#pragma unroll
            for (int mi = 0; mi < 2; mi++)
                ah[mi] = *(const short8*)&sA[(wr + mi * 16 + m16) * LP + ks * 32 + quad * 8];
#pragma unroll
            for (int ni = 0; ni < 8; ni++) {
                const short8 bv = *(const short8*)&sB[(wc + ni * 16 + m16) * LP + ks * 32 + quad * 8];
#pragma unroll
                for (int mi = 0; mi < 2; mi++)
                    acc[mi][ni] = __builtin_amdgcn_mfma_f32_16x16x32_bf16(ah[mi], bv, acc[mi][ni], 0, 0, 0);
            }
        }
        __syncthreads();
    }
    float p[2][4][8] = {};
#pragma unroll
    for (int ni = 0; ni < 8; ni++) {
        const int ocol = wc + ni * 16 + m16;
        const float b1v = bias1[ocol];
        float w2[8];
#pragma unroll
        for (int a = 0; a < 8; a++) w2[a] = W2[ocol * 8 + a];
#pragma unroll
        for (int mi = 0; mi < 2; mi++)
#pragma unroll
            for (int r = 0; r < 4; r++) {
                const float v = fmaxf(acc[mi][ni][r] + b1v, 0.f);
#pragma unroll
                for (int a = 0; a < 8; a++) p[mi][r][a] = fmaf(v, w2[a], p[mi][r][a]);
            }
    }
#pragma unroll
    for (int off = 1; off < 16; off <<= 1)
#pragma unroll
        for (int mi = 0; mi < 2; mi++)
#pragma unroll
            for (int r = 0; r < 4; r++)
#pragma unroll
                for (int a = 0; a < 8; a++) p[mi][r][a] += __shfl_xor(p[mi][r][a], off);
    if (m16 == 0) {
        const int half = wc >> 7;
#pragma unroll
        for (int mi = 0; mi < 2; mi++) {
            const int lrow = wr + mi * 16 + quad * 4;
#pragma unroll
            for (int r = 0; r < 4; r++)
#pragma unroll
                for (int a = 0; a < 8; a++) pLDS[half][lrow + r][a] = p[mi][r][a];
        }
    }
    __syncthreads();
#pragma unroll
    for (int u = 0; u < 2; u++) {
        const int idx = tid * 2 + u;
        const int lrow = idx >> 3, a = idx & 7;
        const int orow = row0 + lrow;
        if (orow < M && a < Aout)
            out[(size_t)orow * Aout + a] =
                tanhf(pLDS[0][lrow][a] + pLDS[1][lrow][a] + bias2[a]);
    }
}
#undef LP

// ---------------- CSR build ----------------
__global__ void count_kernel(const int* __restrict__ dstA, int* __restrict__ deg, int E, int Etot) {
    const int e = blockIdx.x * blockDim.x + threadIdx.x;
    if (e >= Etot) return;
    const int d = (e < E) ? dstA[e] : (e - E);
    atomicAdd(&deg[d], 1);
}

__global__ __launch_bounds__(1024) void scan_kernel(const int* __restrict__ deg,
                                                    int* __restrict__ offs,
                                                    int* __restrict__ cursor, int N) {
    __shared__ int sums[1024];
    const int t = threadIdx.x;
    const int chunk = (N + 1023) / 1024;
    const int start = t * chunk;
    int s = 0;
    for (int i = 0; i < chunk; i++) {
        const int p = start + i;
        if (p < N) s += deg[p];
    }
    sums[t] = s;
    __syncthreads();
    for (int off = 1; off < 1024; off <<= 1) {
        const int add = (t >= off) ? sums[t - off] : 0;
        __syncthreads();
        sums[t] += add;
        __syncthreads();
    }
    int run = (t > 0) ? sums[t - 1] : 0;
    for (int i = 0; i < chunk; i++) {
        const int p = start + i;
        if (p < N) { offs[p] = run; cursor[p] = run; run += deg[p]; }
    }
    if (t == 0) offs[N] = sums[1023];
}

// writes src index into edata[slot].x
__global__ void scatter_kernel(const int* __restrict__ srcA, const int* __restrict__ dstA,
                               int* __restrict__ cursor, int2* __restrict__ edata, int E, int Etot) {
    const int e = blockIdx.x * blockDim.x + threadIdx.x;
    if (e >= Etot) return;
    int s, d;
    if (e < E) { s = srcA[e]; d = dstA[e]; } else { s = d = e - E; }
    const int slot = atomicAdd(&cursor[d], 1);
    edata[slot].x = s;
}

// ---- per-edge softmax weights: w_j = exp(leaky(as[s_j]+ad[n])), once/edge ---
__global__ __launch_bounds__(256) void edge_alpha(const float* __restrict__ as_,
                                                  const float* __restrict__ ad_,
                                                  const int* __restrict__ offs,
                                                  int2* __restrict__ edata,
                                                  float* __restrict__ denom, int N) {
    const int n = blockIdx.x * 4 + (threadIdx.x >> 6);
    if (n >= N) return;
    const int lane = threadIdx.x & 63;
    const int b = offs[n], e2 = offs[n + 1];
    const float adn = ad_[n];
    float sum = 0.f;
    for (int j = b + lane; j < e2; j += 64) {
        const int s = edata[j].x;
        float v = as_[s] + adn;
        v = v > 0.f ? v : 0.2f * v;
        const float w = __expf(v);
        edata[j].y = __float_as_int(w);
        sum += w;
    }
#pragma unroll
    for (int off = 32; off; off >>= 1) sum += __shfl_down(sum, off);
    if (lane == 0) denom[n] = sum;
}

// ---- aggregation: wave per node, 4 feats/lane (us4), precomputed weights ----
// 16-edge clamp-unroll: 16 x 512B row reads in flight per wave (64 lines).
// n wave-uniform via readfirstlane -> edata/offs/denom on scalar pipe.
__global__ __launch_bounds__(256) void agg_kernel(const unsigned short* __restrict__ hb,
                                                  const int* __restrict__ offs,
                                                  const int2* __restrict__ edata,
                                                  const float* __restrict__ denom,
                                                  const float* __restrict__ bias,
                                                  unsigned short* __restrict__ xout, int N) {
    const int n = __builtin_amdgcn_readfirstlane(blockIdx.x * 4 + (threadIdx.x >> 6));
    if (n >= N) return;
    const int f0 = (threadIdx.x & 63) * 4;
    const int b = offs[n], e2 = offs[n + 1];
    float a0 = 0.f, a1 = 0.f, a2 = 0.f, a3 = 0.f;
    for (int j = b; j < e2; j += 16) {
        float w[16];
        int src[16];
#pragma unroll
        for (int u = 0; u < 16; u++) {
            const int jj = (j + u < e2) ? (j + u) : (e2 - 1);   // clamp: self-loop guarantees valid
            const int2 ew = edata[jj];
            src[u] = ew.x;
            w[u] = (j + u < e2) ? __int_as_float(ew.y) : 0.f;
        }
        us4 pv[16];
#pragma unroll
        for (int u = 0; u < 16; u++) pv[u] = *(const us4*)(hb + (unsigned)((src[u] << 8) + f0));
#pragma unroll
        for (int u = 0; u < 16; u++) {
            a0 = fmaf(w[u], us2f(pv[u][0]), a0);
            a1 = fmaf(w[u], us2f(pv[u][1]), a1);
            a2 = fmaf(w[u], us2f(pv[u][2]), a2);
            a3 = fmaf(w[u], us2f(pv[u][3]), a3);
        }
    }
    const float inv = 1.0f / (denom[n] + 1e-16f);
    us4 o;
    o[0] = f2us_rtn(fmaxf(a0 * inv + bias[f0], 0.f));
    o[1] = f2us_rtn(fmaxf(a1 * inv + bias[f0 + 1], 0.f));
    o[2] = f2us_rtn(fmaxf(a2 * inv + bias[f0 + 2], 0.f));
    o[3] = f2us_rtn(fmaxf(a3 * inv + bias[f0 + 3], 0.f));
    *(us4*)(xout + (unsigned)((n << 8) + f0)) = o;
}

extern "C" void kernel_launch(void* const* d_in, const int* in_sizes, int n_in,
                              void* d_out, int out_size, void* d_ws, size_t ws_size,
                              hipStream_t stream) {
    const float* obs = (const float*)d_in[0];
    const int* eidx  = (const int*)d_in[1];
    const float* W1  = (const float*)d_in[2];
    const float* a1s = (const float*)d_in[3];
    const float* a1d = (const float*)d_in[4];
    const float* b1  = (const float*)d_in[5];
    const float* W2  = (const float*)d_in[6];
    const float* a2s = (const float*)d_in[7];
    const float* a2d = (const float*)d_in[8];
    const float* b2v = (const float*)d_in[9];
    const float* Wm1 = (const float*)d_in[10];
    const float* bm1 = (const float*)d_in[11];
    const float* Wm2 = (const float*)d_in[12];
    const float* bm2 = (const float*)d_in[13];
    float* out = (float*)d_out;

    const int Hh = in_sizes[3];            // 256
    const int Dd = in_sizes[2] / Hh;       // 256
    const int N  = in_sizes[0] / Dd;       // 20000
    const int E  = in_sizes[1] / 2;        // 320000
    const int Etot = E + N;                // 340000 (with self-loops)
    const int Aout = in_sizes[12] / Hh;    // 8

    const int* srcA = eidx;
    const int* dstA = eidx + E;

    size_t off = 0;
    char* ws = (char*)d_ws;
    auto alloc = [&](size_t bytes) -> char* {
        char* p = ws + off;
        off = (off + bytes + 15) & ~(size_t)15;
        return p;
    };
    unsigned short* h  = (unsigned short*)alloc((size_t)N * Hh * 2);
    unsigned short* xb = (unsigned short*)alloc((size_t)N * Hh * 2);
    float* as1   = (float*)alloc((size_t)N * 4);
    float* ad1   = (float*)alloc((size_t)N * 4);
    float* as2   = (float*)alloc((size_t)N * 4);
    float* ad2   = (float*)alloc((size_t)N * 4);
    float* denom = (float*)alloc((size_t)N * 4);
    int* deg     = (int*)alloc((size_t)N * 4);
    int* offs    = (int*)alloc((size_t)(N + 1) * 4);
    int* cursor  = (int*)alloc((size_t)N * 4);
    int2* edata  = (int2*)alloc((size_t)Etot * 8);
    const size_t wsz = (size_t)Dd * Hh;    // 65536
    unsigned short* W1t = (unsigned short*)alloc(wsz * 2);
    unsigned short* W2t = (unsigned short*)alloc(wsz * 2);
    unsigned short* Wmt = (unsigned short*)alloc(wsz * 2);

    const int eb = 256;
    const int eg = (Etot + eb - 1) / eb;
    const dim3 ggrid((N + 63) / 64, Hh / 128);   // 313 x 2
    const int nrow = (N + 63) / 64;              // 313
    const int nb4 = (N + 3) / 4;

    // ---- prep ----
    const int ptot = 3 * (int)wsz + 5 * N;
    prep_all<<<(ptot + 255) / 256, 256, 0, stream>>>(
        W1, W2, Wm1, W1t, W2t, Wmt, as1, ad1, as2, ad2, deg, Dd, Hh, N);

    // ---- CSR build ----
    count_kernel<<<eg, eb, 0, stream>>>(dstA, deg, E, Etot);
    scan_kernel<<<1, 1024, 0, stream>>>(deg, offs, cursor, N);
    scatter_kernel<<<eg, eb, 0, stream>>>(srcA, dstA, cursor, edata, E, Etot);

    // ---- GAT layer 1 (fp32 A staged->bf16 in-kernel) ----
    gemm_mfma<float><<<ggrid, 256, 0, stream>>>(obs, W1t, a1s, a1d, as1, ad1, h, N, Hh, Dd);
    edge_alpha<<<nb4, 256, 0, stream>>>(as1, ad1, offs, edata, denom, N);
    agg_kernel<<<nb4, 256, 0, stream>>>(h, offs, edata, denom, b1, xb, N);

    // ---- GAT layer 2 ----
    gemm_mfma<unsigned short><<<ggrid, 256, 0, stream>>>(xb, W2t, a2s, a2d, as2, ad2, h, N, Hh, Hh);
    edge_alpha<<<nb4, 256, 0, stream>>>(as2, ad2, offs, edata, denom, N);
    agg_kernel<<<nb4, 256, 0, stream>>>(h, offs, edata, denom, b2v, xb, N);

    // ---- MLP + head (fused) ----
    gemm_head<<<nrow, 256, 0, stream>>>(xb, Wmt, bm1, Wm2, bm2, out, N, Hh, Aout);
}

// Round 17
// 263.699 us; speedup vs baseline: 1.2300x; 1.0250x over previous
//
#include <hip/hip_runtime.h>
#include <hip/hip_bf16.h>
#include <math.h>
#include <stdio.h>

typedef __attribute__((ext_vector_type(8))) short short8;   // 8 bf16 (4 VGPRs)
typedef __attribute__((ext_vector_type(4))) float f32x4;
typedef __attribute__((ext_vector_type(4))) unsigned short us4;

__device__ __forceinline__ float us2f(unsigned short u) {
    return __uint_as_float(((unsigned)u) << 16);
}
__device__ __forceinline__ unsigned short f2us_rtn(float f) {
    return (unsigned short)__bfloat16_as_ushort(__float2bfloat16(f));  // RTN
}

// A-staging loaders: bf16 copy, or fp32 -> bf16 (RTN) convert
__device__ __forceinline__ void stage8(const unsigned short* Ap, unsigned short* dst) {
    *(short8*)dst = *(const short8*)Ap;
}
__device__ __forceinline__ void stage8(const float* Ap, unsigned short* dst) {
    const float4 a = *(const float4*)Ap;
    const float4 b = *(const float4*)(Ap + 4);
    const float f[8] = {a.x, a.y, a.z, a.w, b.x, b.y, b.z, b.w};
    short8 o;
#pragma unroll
    for (int e = 0; e < 8; e++) o[e] = (short)f2us_rtn(f[e]);
    *(short8*)dst = o;
}

// ---- prep: W^T bf16 x3 + zero-init (deg, as/ad x4) --------------------------
__global__ void prep_all(const float* __restrict__ Wa, const float* __restrict__ Wb,
                         const float* __restrict__ Wc,
                         unsigned short* __restrict__ TA, unsigned short* __restrict__ TB,
                         unsigned short* __restrict__ TC,
                         float* __restrict__ as1, float* __restrict__ ad1,
                         float* __restrict__ as2, float* __restrict__ ad2,
                         int* __restrict__ deg,
                         int K, int Nn, int N) {
    const int tot = K * Nn;
    int idx = blockIdx.x * blockDim.x + threadIdx.x;
    if (idx < 3 * tot) {
        const float* W;
        unsigned short* T;
        if (idx < tot) { W = Wa; T = TA; }
        else if (idx < 2 * tot) { W = Wb; T = TB; idx -= tot; }
        else { W = Wc; T = TC; idx -= 2 * tot; }
        const int n = idx / K, k = idx - n * K;
        T[idx] = f2us_rtn(W[(size_t)k * Nn + n]);
        return;
    }
    idx -= 3 * tot;
    if (idx < 5 * N) {
        if (idx < N) as1[idx] = 0.f;
        else if (idx < 2 * N) ad1[idx - N] = 0.f;
        else if (idx < 3 * N) as2[idx - 2 * N] = 0.f;
        else if (idx < 4 * N) ad2[idx - 3 * N] = 0.f;
        else deg[idx - 4 * N] = 0;
    }
}

#define LP 72
// ---------------- MFMA GEMM + fused dots (GAT layers 1/2) --------------------
// 64x128 tile/block, BK=64, 256 thr (4 waves 2x2). A fp32 or bf16; B bf16.
template <typename TA>
__global__ __launch_bounds__(256) void gemm_mfma(const TA* __restrict__ A,
                                                 const unsigned short* __restrict__ Bt,
                                                 const float* __restrict__ avs,
                                                 const float* __restrict__ avd,
                                                 float* __restrict__ as_,
                                                 float* __restrict__ ad_,
                                                 unsigned short* __restrict__ C,
                                                 int M, int Nn, int K) {
    __shared__ unsigned short sA[64 * LP];
    __shared__ unsigned short sB[128 * LP];
    const int tid = threadIdx.x;
    const int wave = tid >> 6, lane = tid & 63;
    const int m16 = lane & 15, quad = lane >> 4;
    const int row0 = blockIdx.x * 64, col0 = blockIdx.y * 128;
    const int wr = (wave >> 1) * 32, wc = (wave & 1) * 64;
    const int ar = tid >> 2, akc = (tid & 3) * 8;
    const int bkc = (tid & 7) * 8, bcb = tid >> 3;

    f32x4 acc[2][4] = {};
    for (int k0 = 0; k0 < K; k0 += 64) {
        {
            const int gr = (row0 + ar) < M ? (row0 + ar) : (M - 1);
            const TA* Ap = A + (size_t)gr * K + k0 + akc;
            stage8(Ap,      &sA[ar * LP + akc]);
            stage8(Ap + 32, &sA[ar * LP + akc + 32]);
        }
#pragma unroll
        for (int q = 0; q < 4; q++) {
            const int colq = bcb + 32 * q;
            *(short8*)&sB[colq * LP + bkc] =
                *(const short8*)(Bt + (size_t)(col0 + colq) * K + k0 + bkc);
        }
        __syncthreads();
#pragma unroll
        for (int ks = 0; ks < 2; ks++) {
            short8 ah[2];
#pragma unroll
            for (int mi = 0; mi < 2; mi++)
                ah[mi] = *(const short8*)&sA[(wr + mi * 16 + m16) * LP + ks * 32 + quad * 8];
#pragma unroll
            for (int ni = 0; ni < 4; ni++) {
                const short8 bv = *(const short8*)&sB[(wc + ni * 16 + m16) * LP + ks * 32 + quad * 8];
#pragma unroll
                for (int mi = 0; mi < 2; mi++)
                    acc[mi][ni] = __builtin_amdgcn_mfma_f32_16x16x32_bf16(ah[mi], bv, acc[mi][ni], 0, 0, 0);
            }
        }
        __syncthreads();
    }
    // epilogue: C/D layout col=lane&15, row=quad*4+r [m89-verified]
    float ps[2][4] = {}, pd[2][4] = {};
#pragma unroll
    for (int mi = 0; mi < 2; mi++) {
        const int orow_base = row0 + wr + mi * 16 + quad * 4;
#pragma unroll
        for (int ni = 0; ni < 4; ni++) {
            const int ocol = col0 + wc + ni * 16 + m16;
            const float asv = avs[ocol], adv = avd[ocol];
#pragma unroll
            for (int r = 0; r < 4; r++) {
                const int orow = orow_base + r;
                if (orow < M) {
                    const float v = acc[mi][ni][r];
                    C[(size_t)orow * Nn + ocol] = f2us_rtn(v);
                    ps[mi][r] = fmaf(v, asv, ps[mi][r]);
                    pd[mi][r] = fmaf(v, adv, pd[mi][r]);
                }
            }
        }
    }
#pragma unroll
    for (int mi = 0; mi < 2; mi++)
#pragma unroll
        for (int r = 0; r < 4; r++)
#pragma unroll
            for (int off = 1; off < 16; off <<= 1) {
                ps[mi][r] += __shfl_xor(ps[mi][r], off);
                pd[mi][r] += __shfl_xor(pd[mi][r], off);
            }
    if (m16 == 0) {
#pragma unroll
        for (int mi = 0; mi < 2; mi++) {
            const int orow_base = row0 + wr + mi * 16 + quad * 4;
#pragma unroll
            for (int r = 0; r < 4; r++) {
                const int orow = orow_base + r;
                if (orow < M) {
                    atomicAdd(&as_[orow], ps[mi][r]);
                    atomicAdd(&ad_[orow], pd[mi][r]);
                }
            }
        }
    }
}

// ---------------- MLP gemm + fused head: out = tanh(relu(x@Wm1+bm1)@Wm2+bm2) -
__global__ __launch_bounds__(256) void gemm_head(const unsigned short* __restrict__ A,
                                                 const unsigned short* __restrict__ Bt,
                                                 const float* __restrict__ bias1,
                                                 const float* __restrict__ W2,
                                                 const float* __restrict__ bias2,
                                                 float* __restrict__ out,
                                                 int M, int K, int Aout) {
    __shared__ unsigned short sA[64 * LP];
    __shared__ unsigned short sB[256 * LP];
    __shared__ float pLDS[2][64][8];
    const int tid = threadIdx.x;
    const int wave = tid >> 6, lane = tid & 63;
    const int m16 = lane & 15, quad = lane >> 4;
    const int row0 = blockIdx.x * 64;
    const int wr = (wave >> 1) * 32, wc = (wave & 1) * 128;
    const int ar = tid >> 2, akc = (tid & 3) * 8;
    const int bkc = (tid & 7) * 8, bcb = tid >> 3;

    f32x4 acc[2][8] = {};
    for (int k0 = 0; k0 < K; k0 += 64) {
        {
            const int gr = (row0 + ar) < M ? (row0 + ar) : (M - 1);
            const unsigned short* Ap = A + (size_t)gr * K + k0 + akc;
            *(short8*)&sA[ar * LP + akc]      = *(const short8*)Ap;
            *(short8*)&sA[ar * LP + akc + 32] = *(const short8*)(Ap + 32);
        }
#pragma unroll
        for (int q = 0; q < 8; q++) {
            const int colq = bcb + 32 * q;
            *(short8*)&sB[colq * LP + bkc] =
                *(const short8*)(Bt + (size_t)colq * K + k0 + bkc);
        }
        __syncthreads();
#pragma unroll
        for (int ks = 0; ks < 2; ks++) {
            short8 ah[2];
#pragma unroll
            for (int mi = 0; mi < 2; mi++)
                ah[mi] = *(const short8*)&sA[(wr + mi * 16 + m16) * LP + ks * 32 + quad * 8];
#pragma unroll
            for (int ni = 0; ni < 8; ni++) {
                const short8 bv = *(const short8*)&sB[(wc + ni * 16 + m16) * LP + ks * 32 + quad * 8];
#pragma unroll
                for (int mi = 0; mi < 2; mi++)
                    acc[mi][ni] = __builtin_amdgcn_mfma_f32_16x16x32_bf16(ah[mi], bv, acc[mi][ni], 0, 0, 0);
            }
        }
        __syncthreads();
    }
    float p[2][4][8] = {};
#pragma unroll
    for (int ni = 0; ni < 8; ni++) {
        const int ocol = wc + ni * 16 + m16;
        const float b1v = bias1[ocol];
        float w2[8];
#pragma unroll
        for (int a = 0; a < 8; a++) w2[a] = W2[ocol * 8 + a];
#pragma unroll
        for (int mi = 0; mi < 2; mi++)
#pragma unroll
            for (int r = 0; r < 4; r++) {
                const float v = fmaxf(acc[mi][ni][r] + b1v, 0.f);
#pragma unroll
                for (int a = 0; a < 8; a++) p[mi][r][a] = fmaf(v, w2[a], p[mi][r][a]);
            }
    }
#pragma unroll
    for (int off = 1; off < 16; off <<= 1)
#pragma unroll
        for (int mi = 0; mi < 2; mi++)
#pragma unroll
            for (int r = 0; r < 4; r++)
#pragma unroll
                for (int a = 0; a < 8; a++) p[mi][r][a] += __shfl_xor(p[mi][r][a], off);
    if (m16 == 0) {
        const int half = wc >> 7;
#pragma unroll
        for (int mi = 0; mi < 2; mi++) {
            const int lrow = wr + mi * 16 + quad * 4;
#pragma unroll
            for (int r = 0; r < 4; r++)
#pragma unroll
                for (int a = 0; a < 8; a++) pLDS[half][lrow + r][a] = p[mi][r][a];
        }
    }
    __syncthreads();
#pragma unroll
    for (int u = 0; u < 2; u++) {
        const int idx = tid * 2 + u;
        const int lrow = idx >> 3, a = idx & 7;
        const int orow = row0 + lrow;
        if (orow < M && a < Aout)
            out[(size_t)orow * Aout + a] =
                tanhf(pLDS[0][lrow][a] + pLDS[1][lrow][a] + bias2[a]);
    }
}
#undef LP

// ---------------- CSR build ----------------
__global__ void count_kernel(const int* __restrict__ dstA, int* __restrict__ deg, int E, int Etot) {
    const int e = blockIdx.x * blockDim.x + threadIdx.x;
    if (e >= Etot) return;
    const int d = (e < E) ? dstA[e] : (e - E);
    atomicAdd(&deg[d], 1);
}

__global__ __launch_bounds__(1024) void scan_kernel(const int* __restrict__ deg,
                                                    int* __restrict__ offs,
                                                    int* __restrict__ cursor, int N) {
    __shared__ int sums[1024];
    const int t = threadIdx.x;
    const int chunk = (N + 1023) / 1024;
    const int start = t * chunk;
    int s = 0;
    for (int i = 0; i < chunk; i++) {
        const int p = start + i;
        if (p < N) s += deg[p];
    }
    sums[t] = s;
    __syncthreads();
    for (int off = 1; off < 1024; off <<= 1) {
        const int add = (t >= off) ? sums[t - off] : 0;
        __syncthreads();
        sums[t] += add;
        __syncthreads();
    }
    int run = (t > 0) ? sums[t - 1] : 0;
    for (int i = 0; i < chunk; i++) {
        const int p = start + i;
        if (p < N) { offs[p] = run; cursor[p] = run; run += deg[p]; }
    }
    if (t == 0) offs[N] = sums[1023];
}

__global__ void scatter_kernel(const int* __restrict__ srcA, const int* __restrict__ dstA,
                               int* __restrict__ cursor, int* __restrict__ esrc, int E, int Etot) {
    const int e = blockIdx.x * blockDim.x + threadIdx.x;
    if (e >= Etot) return;
    int s, d;
    if (e < E) { s = srcA[e]; d = dstA[e]; } else { s = d = e - E; }
    const int slot = atomicAdd(&cursor[d], 1);
    esrc[slot] = s;
}

// ---- fused softmax+aggregation: wave/node, in-wave exp dedup + 16-unroll ----
// Per 16-edge chunk: lanes 0-15 compute w=exp(leaky(as[s]+ad[n])) ONCE per
// edge; (s,w) broadcast to all lanes via readlane; 16 x 512B gathers in
// flight; wsum tree-reduced at end (no denom buffer, no edge_alpha pass).
__global__ __launch_bounds__(256) void agg_kernel(const unsigned short* __restrict__ hb,
                                                  const int* __restrict__ offs,
                                                  const int* __restrict__ esrc,
                                                  const float* __restrict__ as_,
                                                  const float* __restrict__ ad_,
                                                  const float* __restrict__ bias,
                                                  unsigned short* __restrict__ xout, int N) {
    const int n = __builtin_amdgcn_readfirstlane(blockIdx.x * 4 + (threadIdx.x >> 6));
    if (n >= N) return;
    const int lane = threadIdx.x & 63;
    const int f0 = lane * 4;
    const int b = offs[n], e2 = offs[n + 1];
    const float adn = ad_[n];
    float a0 = 0.f, a1 = 0.f, a2 = 0.f, a3 = 0.f, wsum = 0.f;
    for (int c0 = b; c0 < e2; c0 += 16) {
        // phase 1: lanes 0-15 own edges c0..c0+15
        int s = 0;
        float w = 0.f;
        if (lane < 16) {
            const int j = c0 + lane;
            const int jj = j < e2 ? j : e2 - 1;     // self-loop guarantees >= 1 edge
            s = esrc[jj];
            if (j < e2) {
                float v = as_[s] + adn;
                v = v > 0.f ? v : 0.2f * v;
                w = __expf(v);
                wsum += w;
            }
        }
        // phase 2: broadcast (readlane) + deep gather + fma
        int sb[16];
        float wb[16];
#pragma unroll
        for (int u = 0; u < 16; u++) {
            sb[u] = __shfl(s, u);
            wb[u] = __shfl(w, u);
        }
        us4 pv[16];
#pragma unroll
        for (int u = 0; u < 16; u++)
            pv[u] = *(const us4*)(hb + (unsigned)((sb[u] << 8) + f0));
#pragma unroll
        for (int u = 0; u < 16; u++) {
            a0 = fmaf(wb[u], us2f(pv[u][0]), a0);
            a1 = fmaf(wb[u], us2f(pv[u][1]), a1);
            a2 = fmaf(wb[u], us2f(pv[u][2]), a2);
            a3 = fmaf(wb[u], us2f(pv[u][3]), a3);
        }
    }
#pragma unroll
    for (int off = 32; off; off >>= 1) wsum += __shfl_xor(wsum, off);
    const float inv = 1.0f / (wsum + 1e-16f);
    us4 o;
    o[0] = f2us_rtn(fmaxf(a0 * inv + bias[f0], 0.f));
    o[1] = f2us_rtn(fmaxf(a1 * inv + bias[f0 + 1], 0.f));
    o[2] = f2us_rtn(fmaxf(a2 * inv + bias[f0 + 2], 0.f));
    o[3] = f2us_rtn(fmaxf(a3 * inv + bias[f0 + 3], 0.f));
    *(us4*)(xout + (unsigned)((n << 8) + f0)) = o;
}

extern "C" void kernel_launch(void* const* d_in, const int* in_sizes, int n_in,
                              void* d_out, int out_size, void* d_ws, size_t ws_size,
                              hipStream_t stream) {
    const float* obs = (const float*)d_in[0];
    const int* eidx  = (const int*)d_in[1];
    const float* W1  = (const float*)d_in[2];
    const float* a1s = (const float*)d_in[3];
    const float* a1d = (const float*)d_in[4];
    const float* b1  = (const float*)d_in[5];
    const float* W2  = (const float*)d_in[6];
    const float* a2s = (const float*)d_in[7];
    const float* a2d = (const float*)d_in[8];
    const float* b2v = (const float*)d_in[9];
    const float* Wm1 = (const float*)d_in[10];
    const float* bm1 = (const float*)d_in[11];
    const float* Wm2 = (const float*)d_in[12];
    const float* bm2 = (const float*)d_in[13];
    float* out = (float*)d_out;

    const int Hh = in_sizes[3];            // 256
    const int Dd = in_sizes[2] / Hh;       // 256
    const int N  = in_sizes[0] / Dd;       // 20000
    const int E  = in_sizes[1] / 2;        // 320000
    const int Etot = E + N;                // 340000 (with self-loops)
    const int Aout = in_sizes[12] / Hh;    // 8

    const int* srcA = eidx;
    const int* dstA = eidx + E;

    size_t off = 0;
    char* ws = (char*)d_ws;
    auto alloc = [&](size_t bytes) -> char* {
        char* p = ws + off;
        off = (off + bytes + 15) & ~(size_t)15;
        return p;
    };
    unsigned short* h  = (unsigned short*)alloc((size_t)N * Hh * 2);
    unsigned short* xb = (unsigned short*)alloc((size_t)N * Hh * 2);
    float* as1   = (float*)alloc((size_t)N * 4);
    float* ad1   = (float*)alloc((size_t)N * 4);
    float* as2   = (float*)alloc((size_t)N * 4);
    float* ad2   = (float*)alloc((size_t)N * 4);
    int* deg     = (int*)alloc((size_t)N * 4);
    int* offs    = (int*)alloc((size_t)(N + 1) * 4);
    int* cursor  = (int*)alloc((size_t)N * 4);
    int* esrc    = (int*)alloc((size_t)Etot * 4);
    const size_t wsz = (size_t)Dd * Hh;    // 65536
    unsigned short* W1t = (unsigned short*)alloc(wsz * 2);
    unsigned short* W2t = (unsigned short*)alloc(wsz * 2);
    unsigned short* Wmt = (unsigned short*)alloc(wsz * 2);

    const int eb = 256;
    const int eg = (Etot + eb - 1) / eb;
    const dim3 ggrid((N + 63) / 64, Hh / 128);   // 313 x 2
    const int nrow = (N + 63) / 64;              // 313
    const int nb4 = (N + 3) / 4;

    // ---- prep ----
    const int ptot = 3 * (int)wsz + 5 * N;
    prep_all<<<(ptot + 255) / 256, 256, 0, stream>>>(
        W1, W2, Wm1, W1t, W2t, Wmt, as1, ad1, as2, ad2, deg, Dd, Hh, N);

    // ---- CSR build ----
    count_kernel<<<eg, eb, 0, stream>>>(dstA, deg, E, Etot);
    scan_kernel<<<1, 1024, 0, stream>>>(deg, offs, cursor, N);
    scatter_kernel<<<eg, eb, 0, stream>>>(srcA, dstA, cursor, esrc, E, Etot);

    // ---- GAT layer 1 (fp32 A staged->bf16 in-kernel) ----
    gemm_mfma<float><<<ggrid, 256, 0, stream>>>(obs, W1t, a1s, a1d, as1, ad1, h, N, Hh, Dd);
    agg_kernel<<<nb4, 256, 0, stream>>>(h, offs, esrc, as1, ad1, b1, xb, N);

    // ---- GAT layer 2 ----
    gemm_mfma<unsigned short><<<ggrid, 256, 0, stream>>>(xb, W2t, a2s, a2d, as2, ad2, h, N, Hh, Hh);
    agg_kernel<<<nb4, 256, 0, stream>>>(h, offs, esrc, as2, ad2, b2v, xb, N);

    // ---- MLP + head (fused) ----
    gemm_head<<<nrow, 256, 0, stream>>>(xb, Wmt, bm1, Wm2, bm2, out, N, Hh, Aout);
}